// Round 9
// baseline (205.060 us; speedup 1.0000x reference)
//
#include <hip/hip_runtime.h>
#include <hip/hip_bf16.h>

#define N_NODES 50000
#define N_EDGES 800000
#define EMB 64
#define HID 64
#define N_CLASSES 10
#define N_GRAPHS 512

#define BKT_SHIFT 6
#define BKT_NODES 64
#define NB_BKT ((N_NODES + BKT_NODES - 1) / BKT_NODES)   // 782
#define BKT_CAP 1408     // mean 1024 + 12 sigma
#define CNT_STRIDE 16    // one counter per 64B line: kills cross-XCD false sharing
#define EB_CHUNK 4096
#define EB_PER_THR (EB_CHUNK / 256)                      // 16
#define EB_BLOCKS ((N_EDGES + EB_CHUNK - 1) / EB_CHUNK)  // 196
#define XFORM_BLOCKS ((N_NODES + 63) / 64)               // 782
#define XPAD 68
#define ZROW N_NODES                                      // sentinel zero-row
#define HALF_SRC 25000                                    // src-phase boundary
#define NKEY 128          // 64 local dst x 2 src-halves
#define LCSR_SZ 1792      // 1408 + 128 keys * 3 max pad (pad-to-4)
#define LCSR_FULL 1800    // +8 guard for empty trailing regions
#define NXCD 8
#define CPY ((size_t)(N_NODES + 1) * 64)                  // elements per copy

// bf16 row accumulate: 8 bf16 dims (uint4) into fp32[8]
#define ACC8(vv, A)                                                            \
    do {                                                                       \
        A[0] += __uint_as_float((vv).x << 16);                                 \
        A[1] += __uint_as_float((vv).x & 0xFFFF0000u);                         \
        A[2] += __uint_as_float((vv).y << 16);                                 \
        A[3] += __uint_as_float((vv).y & 0xFFFF0000u);                         \
        A[4] += __uint_as_float((vv).z << 16);                                 \
        A[5] += __uint_as_float((vv).z & 0xFFFF0000u);                         \
        A[6] += __uint_as_float((vv).w << 16);                                 \
        A[7] += __uint_as_float((vv).w & 0xFFFF0000u);                         \
    } while (0)

// Physical XCD id of this block's CU (uniform across the block).
// Correctness does not depend on the value: all NXCD copies are identical.
__device__ __forceinline__ int xcd_id() {
    int x;
    asm volatile("s_getreg_b32 %0, hwreg(HW_REG_XCC_ID)" : "=s"(x));
    return x & (NXCD - 1);
}

// Build this bucket's src-phased CSR in LDS. Key = localdst*2 + (src>=HALF).
// Regions pad-to-4 with ZROW sentinel -> branch-free 4-wide chunks.
__device__ __forceinline__ void build_local_csr2(
    int bucket, const int* __restrict__ cnt, const int* __restrict__ ebuf,
    unsigned short* lcsr, int* nhist, int* sval, int* sexcl, int* ncur,
    int* wtot) {
    int tid = threadIdx.x;
    int bs = bucket * BKT_CAP;
    int ne = min(cnt[bucket * CNT_STRIDE], BKT_CAP);   // defensive clamp
    if (tid < NKEY) { nhist[tid] = 0; ncur[tid] = 0; }
    for (int i = tid; i < LCSR_FULL; i += 256) lcsr[i] = (unsigned short)ZROW;
    __syncthreads();
    int held[6];                 // 6*256 = 1536 >= BKT_CAP
    int nh = 0;
    for (int i = tid; i < ne; i += 256) held[nh++] = ebuf[bs + i];
#pragma unroll
    for (int j = 0; j < 6; j++)
        if (j < nh) {
            int p = held[j];
            int key = ((p >> 16) << 1) | (((p & 0xFFFF) >= HALF_SRC) ? 1 : 0);
            atomicAdd(&nhist[key], 1);
        }
    __syncthreads();
    // two-wave scan of 128 PADDED (to 4) region sizes
    int v = 0, pp = 0, s = 0;
    if (tid < NKEY) {
        v = nhist[tid];
        pp = (v + 3) & ~3;
        s = pp;
#pragma unroll
        for (int off = 1; off < 64; off <<= 1) {
            int u = __shfl_up(s, off, 64);
            if ((tid & 63) >= off) s += u;
        }
        sval[tid] = v;
        if ((tid & 63) == 63) wtot[tid >> 6] = s;
    }
    __syncthreads();
    if (tid < NKEY)
        sexcl[tid] = ((tid >= 64) ? wtot[0] : 0) + s - pp;
    __syncthreads();
#pragma unroll
    for (int j = 0; j < 6; j++)
        if (j < nh) {
            int p = held[j];
            int sidx = p & 0xFFFF;
            int key = ((p >> 16) << 1) | ((sidx >= HALF_SRC) ? 1 : 0);
            int r = atomicAdd(&ncur[key], 1);
            lcsr[sexcl[key] + r] = (unsigned short)sidx;
        }
    __syncthreads();
}

// Dual-node accumulate over one src-class segment pair. 4-wide chunks,
// 2-deep software pipeline; sentinel pads accumulate 0.
__device__ __forceinline__ void agg2_acc(
    int sA, int dA, int sB, int dB, int sl,
    const unsigned short* lcsr, const __hip_bfloat16* __restrict__ Pb,
    float a0[8], float a1[8], float b0[8], float b1[8]) {
    int nA = (dA + 3) >> 2, nB = (dB + 3) >> 2;
    int n = max(nA, nB);
    if (n <= 0) return;
    int mA = max(nA - 1, 0), mB = max(nB - 1, 0);
    uint4 A0[4], A1[4], B0[4], B1[4];
#define LD4(D, base_)                                                          \
    {                                                                          \
        int _p = (base_);                                                      \
        D[0] = ((const uint4*)(Pb + (size_t)lcsr[_p + 0] * 64))[sl];           \
        D[1] = ((const uint4*)(Pb + (size_t)lcsr[_p + 1] * 64))[sl];           \
        D[2] = ((const uint4*)(Pb + (size_t)lcsr[_p + 2] * 64))[sl];           \
        D[3] = ((const uint4*)(Pb + (size_t)lcsr[_p + 3] * 64))[sl];           \
    }
#define AC4(S, X0, X1)                                                         \
    { ACC8(S[0], X0); ACC8(S[1], X1); ACC8(S[2], X0); ACC8(S[3], X1); }
    LD4(A0, sA); LD4(B0, sB);
    int c = 1;
    for (; c + 1 < n; c += 2) {
        LD4(A1, sA + 4 * min(c, mA)); LD4(B1, sB + 4 * min(c, mB));
        if (c - 1 < nA) AC4(A0, a0, a1);
        if (c - 1 < nB) AC4(B0, b0, b1);
        LD4(A0, sA + 4 * min(c + 1, mA)); LD4(B0, sB + 4 * min(c + 1, mB));
        if (c < nA) AC4(A1, a0, a1);
        if (c < nB) AC4(B1, b0, b1);
    }
    if (c < n) {
        LD4(A1, sA + 4 * min(c, mA)); LD4(B1, sB + 4 * min(c, mB));
        if (c - 1 < nA) AC4(A0, a0, a1);
        if (c - 1 < nB) AC4(B0, b0, b1);
        if (c < nA) AC4(A1, a0, a1);
        if (c < nB) AC4(B1, b0, b1);
    } else {
        if (c - 1 < nA) AC4(A0, a0, a1);
        if (c - 1 < nB) AC4(B0, b0, b1);
    }
#undef LD4
#undef AC4
}

// Mean over both src-phases for a node pair. Phase lo first, then hi:
// device-wide the gather target is one 3.2MB half of this XCD's copy.
__device__ __forceinline__ void agg_pair2(
    int k0, int k1, int sl, const unsigned short* lcsr,
    const __hip_bfloat16* __restrict__ Pb,
    const int* sval, const int* sexcl, float oA[8], float oB[8]) {
    float a0[8], a1[8], b0[8], b1[8];
#pragma unroll
    for (int j = 0; j < 8; j++) { a0[j] = 0.f; a1[j] = 0.f; b0[j] = 0.f; b1[j] = 0.f; }
    agg2_acc(sexcl[k0], sval[k0], sexcl[k1], sval[k1], sl, lcsr, Pb,
             a0, a1, b0, b1);                                   // lo src-half
    agg2_acc(sexcl[k0 + 1], sval[k0 + 1], sexcl[k1 + 1], sval[k1 + 1], sl,
             lcsr, Pb, a0, a1, b0, b1);                         // hi src-half
    int dA = sval[k0] + sval[k0 + 1];
    int dB = sval[k1] + sval[k1 + 1];
    float invA = (dA > 0) ? 1.0f / (float)dA : 0.0f;
    float invB = (dB > 0) ? 1.0f / (float)dB : 0.0f;
#pragma unroll
    for (int j = 0; j < 8; j++) {
        oA[j] = (a0[j] + a1[j]) * invA;
        oB[j] = (b0[j] + b1[j]) * invB;
    }
}

// m += Q (from H), relu, stage 8 dims into dst[sl*8..sl*8+7]
__device__ __forceinline__ void finish_row(int node, int sl,
                                           const float* __restrict__ H,
                                           float m[8], float* dst) {
    if (node < N_NODES) {
        size_t off = (size_t)node * 64 + sl * 8;
        float4 q0 = *(const float4*)&H[off];
        float4 q1 = *(const float4*)&H[off + 4];
        m[0] = fmaxf(m[0] + q0.x, 0.f);
        m[1] = fmaxf(m[1] + q0.y, 0.f);
        m[2] = fmaxf(m[2] + q0.z, 0.f);
        m[3] = fmaxf(m[3] + q0.w, 0.f);
        m[4] = fmaxf(m[4] + q1.x, 0.f);
        m[5] = fmaxf(m[5] + q1.y, 0.f);
        m[6] = fmaxf(m[6] + q1.z, 0.f);
        m[7] = fmaxf(m[7] + q1.w, 0.f);
    } else {
#pragma unroll
        for (int j = 0; j < 8; j++) m[j] = 0.f;
    }
    *(float4*)&dst[sl * 8] = make_float4(m[0], m[1], m[2], m[3]);
    *(float4*)&dst[sl * 8 + 4] = make_float4(m[4], m[5], m[6], m[7]);
}

// Fused dual-weight 64x64x64 GEMM from staged sX (256 threads, 4 rows each).
// Pb output written to all NXCD copies (coalesced 8B stores per copy).
__device__ __forceinline__ void gemm_dual_from_sX(
    int tile, int t, const float* sX,
    const float* __restrict__ Wl, const float* __restrict__ Wr,
    const float* __restrict__ bl,
    __hip_bfloat16* __restrict__ Pb, float* __restrict__ Qout) {
    int dg = t & 15, ng = t >> 4;
    float accL[4][4], accR[4][4];
#pragma unroll
    for (int i = 0; i < 4; i++)
#pragma unroll
        for (int j = 0; j < 4; j++) { accL[i][j] = 0.f; accR[i][j] = 0.f; }
#pragma unroll 4
    for (int k = 0; k < 64; k++) {
        float4 wl = ((const float4*)Wl)[k * 16 + dg];
        float4 wr = ((const float4*)Wr)[k * 16 + dg];
#pragma unroll
        for (int i = 0; i < 4; i++) {
            float xv = sX[(ng + i * 16) * XPAD + k];
            accL[i][0] = fmaf(xv, wl.x, accL[i][0]);
            accL[i][1] = fmaf(xv, wl.y, accL[i][1]);
            accL[i][2] = fmaf(xv, wl.z, accL[i][2]);
            accL[i][3] = fmaf(xv, wl.w, accL[i][3]);
            accR[i][0] = fmaf(xv, wr.x, accR[i][0]);
            accR[i][1] = fmaf(xv, wr.y, accR[i][1]);
            accR[i][2] = fmaf(xv, wr.z, accR[i][2]);
            accR[i][3] = fmaf(xv, wr.w, accR[i][3]);
        }
    }
    float4 blv = ((const float4*)bl)[dg];
#pragma unroll
    for (int i = 0; i < 4; i++) {
        int node = tile + ng + i * 16;
        if (node < N_NODES) {
            union { ushort4 u; __hip_bfloat16 h[4]; } pk;
            pk.h[0] = __float2bfloat16(accL[i][0]);
            pk.h[1] = __float2bfloat16(accL[i][1]);
            pk.h[2] = __float2bfloat16(accL[i][2]);
            pk.h[3] = __float2bfloat16(accL[i][3]);
#pragma unroll
            for (int c = 0; c < NXCD; c++)
                *(ushort4*)&Pb[c * CPY + (size_t)node * 64 + dg * 4] = pk.u;
            *(float4*)&Qout[(size_t)node * 64 + dg * 4] =
                make_float4(accR[i][0] + blv.x, accR[i][1] + blv.y,
                            accR[i][2] + blv.z, accR[i][3] + blv.w);
        }
    }
}

// ---------------- combo: bucket multi-split (blocks 0..EB) + layer-0 xform ----------------
__global__ __launch_bounds__(256) void k_combo(
    const int* __restrict__ esrc, const int* __restrict__ edst,
    int* __restrict__ cnt, int* __restrict__ ebuf,
    const int* __restrict__ ids, const float* __restrict__ emb,
    const float* __restrict__ Wl, const float* __restrict__ bl,
    const float* __restrict__ Wr,
    __hip_bfloat16* __restrict__ Pb, __hip_bfloat16* __restrict__ Pb1z,
    float* __restrict__ Qout) {
    __shared__ float sX[64 * XPAD];     // bsplit path aliases as int scratch
    int t = threadIdx.x;
    if (blockIdx.x < EB_BLOCKS) {
        // block 0 zeroes ZROW sentinel rows in ALL copies of Pb0/Pb1.
        // 2 arrays x 8 copies x 8 uint4 = 128 stores.
        if (blockIdx.x == 0 && t < 128) {
            uint4 z = make_uint4(0u, 0u, 0u, 0u);
            __hip_bfloat16* base = (t < 64) ? Pb : Pb1z;
            int c = (t >> 3) & 7, j = t & 7;
            ((uint4*)(base + c * CPY + (size_t)ZROW * 64))[j] = z;
        }
        // ---- bsplit path (single pass over edst; dests in registers) ----
        int* h = (int*)sX;                 // NB_BKT
        int* bbase = h + NB_BKT;           // NB_BKT
        int* cur = bbase + NB_BKT;         // NB_BKT (3*782*4 = 9.4KB < 17.4KB)
        for (int i = t; i < NB_BKT; i += 256) { h[i] = 0; cur[i] = 0; }
        __syncthreads();
        int base = blockIdx.x * EB_CHUNK;
        int end = min(base + EB_CHUNK, N_EDGES);
        int dreg[EB_PER_THR];
        int nd = 0;
        for (int i = base + t; i < end; i += 256) dreg[nd++] = edst[i];
#pragma unroll
        for (int j = 0; j < EB_PER_THR; j++)
            if (j < nd) atomicAdd(&h[dreg[j] >> BKT_SHIFT], 1);
        __syncthreads();
        for (int i = t; i < NB_BKT; i += 256)
            if (h[i]) bbase[i] = i * BKT_CAP + atomicAdd(&cnt[i * CNT_STRIDE], h[i]);
        __syncthreads();
        {
            int j = 0;
            for (int i = base + t; i < end; i += 256, j++) {
                int d = dreg[j], s = esrc[i];
                int b = d >> BKT_SHIFT;
                int r = atomicAdd(&cur[b], 1);
                int slot = bbase[b] + r;
                if (slot < (b + 1) * BKT_CAP)          // defensive clamp
                    ebuf[slot] = ((d & (BKT_NODES - 1)) << 16) | s;
            }
        }
        return;
    }
    // ---- xform0 path: stage emb rows, fused dual GEMM ----
    int tile = (blockIdx.x - EB_BLOCKS) * 64;
    for (int i = t; i < 64 * 16; i += 256) {
        int r = i >> 4, c = i & 15;
        int node = tile + r;
        float4 v = make_float4(0.f, 0.f, 0.f, 0.f);
        if (node < N_NODES)
            v = ((const float4*)(emb + (size_t)ids[node] * 64))[c];
        *(float4*)&sX[r * XPAD + c * 4] = v;
    }
    __syncthreads();
    gemm_dual_from_sX(tile, t, sX, Wl, Wr, bl, Pb, Qout);
}

// ---------------- fused: src-phased CSR + layer-0 aggregate + layer-1 xform ----------------
__global__ __launch_bounds__(256, 4) void k_fused1(
    const int* __restrict__ cnt, const int* __restrict__ ebuf,
    const __hip_bfloat16* __restrict__ Pb0, const float* __restrict__ Wl,
    const float* __restrict__ bl, const float* __restrict__ Wr,
    __hip_bfloat16* __restrict__ Pb1, float* __restrict__ H) {
    __shared__ float sX[64 * XPAD];
    __shared__ unsigned short lcsr[LCSR_FULL];
    __shared__ int nhist[NKEY], sval[NKEY], sexcl[NKEY], ncur[NKEY];
    __shared__ int wtot[2];
    int t = threadIdx.x;
    int tile = blockIdx.x * 64;
    const __hip_bfloat16* Pb0_loc = Pb0 + (size_t)xcd_id() * CPY;
    build_local_csr2(blockIdx.x, cnt, ebuf, lcsr, nhist, sval, sexcl, ncur, wtot);
    // phase (a): src-phased dual-node aggregate from XCD-local copy
    int grp = t >> 3, sl = t & 7;
    int ln0 = grp * 2, ln1 = ln0 + 1;
    float mA[8], mB[8];
    agg_pair2(grp * 4, grp * 4 + 2, sl, lcsr, Pb0_loc, sval, sexcl, mA, mB);
    finish_row(tile + ln0, sl, H, mA, &sX[ln0 * XPAD]);
    finish_row(tile + ln1, sl, H, mB, &sX[ln1 * XPAD]);
    __syncthreads();
    // phase (b): fused dual GEMM -> Pb1 copies (bf16) and H (Q1)
    gemm_dual_from_sX(tile, t, sX, Wl, Wr, bl, Pb1, H);
}

// ---------------- layer-1 aggregate + pooling (block = bucket = 64 nodes) ----------------
__global__ __launch_bounds__(256, 4) void k_agg2_pool(
    const int* __restrict__ cnt, const int* __restrict__ ebuf,
    const __hip_bfloat16* __restrict__ Pb, const float* __restrict__ H,
    const int* __restrict__ batch, float* __restrict__ psum) {
    __shared__ float sPool[64 * 64];
    __shared__ unsigned short lcsr[LCSR_FULL];
    __shared__ int nhist[NKEY], sval[NKEY], sexcl[NKEY], ncur[NKEY];
    __shared__ int wtot[2];
    __shared__ int sLg[64];
    int t = threadIdx.x;
    int nb = blockIdx.x * 64;
    int gmin = batch[nb];
    if (t < 64) {
        int node = nb + t;
        sLg[t] = batch[node < N_NODES ? node : (N_NODES - 1)] - gmin;
    }
    const __hip_bfloat16* Pb_loc = Pb + (size_t)xcd_id() * CPY;
    build_local_csr2(blockIdx.x, cnt, ebuf, lcsr, nhist, sval, sexcl, ncur, wtot);
    int grp = t >> 3, sl = t & 7;
    int ln0 = grp * 2, ln1 = ln0 + 1;
    float mA[8], mB[8];
    agg_pair2(grp * 4, grp * 4 + 2, sl, lcsr, Pb_loc, sval, sexcl, mA, mB);
    finish_row(nb + ln0, sl, H, mA, &sPool[ln0 * 64]);
    finish_row(nb + ln1, sl, H, mB, &sPool[ln1 * 64]);
    __syncthreads();
    // segmented per-dim sum over this bucket's 64 rows (batch sorted).
    int d = t & 63, q = t >> 6;
    int n0 = q * 16;
    float run = 0.f;
    int cur = sLg[n0];
    for (int n = n0; n < n0 + 16; n++) {
        int lg = sLg[n];
        if (lg != cur) {
            if (run != 0.f)
                atomicAdd(&psum[(size_t)(gmin + cur) * 64 + d], run);
            run = 0.f;
            cur = lg;
        }
        run += sPool[n * 64 + d];
    }
    if (run != 0.f)
        atomicAdd(&psum[(size_t)(gmin + cur) * 64 + d], run);
}

// ---------------- output projection ----------------
__device__ __forceinline__ int lower_bound_batch(const int* __restrict__ batch, int val) {
    int lo = 0, hi = N_NODES;
    while (lo < hi) {
        int mid = (lo + hi) >> 1;
        if (batch[mid] < val) lo = mid + 1; else hi = mid;
    }
    return lo;
}

__global__ __launch_bounds__(256) void k_out(
    const int* __restrict__ batch, const float* __restrict__ psum,
    const float* __restrict__ Wout, const float* __restrict__ bout,
    float* __restrict__ out) {
    int w = threadIdx.x >> 6, lane = threadIdx.x & 63;
    int g = blockIdx.x * 4 + w;
    if (g >= N_GRAPHS) return;
    int s0 = lower_bound_batch(batch, g);
    int s1 = lower_bound_batch(batch, g + 1);
    int cntg = s1 - s0;
    float inv = (cntg > 0) ? 1.0f / (float)cntg : 0.0f;
    float pooled = psum[(size_t)g * 64 + lane] * inv;
#pragma unroll
    for (int c = 0; c < N_CLASSES; c++) {
        float v = pooled * Wout[lane * N_CLASSES + c];
#pragma unroll
        for (int off = 32; off > 0; off >>= 1) v += __shfl_down(v, off, 64);
        if (lane == 0) out[(size_t)g * N_CLASSES + c] = v + bout[c];
    }
}

// ---------------- launch ----------------

extern "C" void kernel_launch(void* const* d_in, const int* in_sizes, int n_in,
                              void* d_out, int out_size, void* d_ws, size_t ws_size,
                              hipStream_t stream) {
    const int*   node_ids = (const int*)d_in[0];
    const int*   edge_idx = (const int*)d_in[1];   // [2, E] row-major
    const int*   batch    = (const int*)d_in[2];
    const float* emb      = (const float*)d_in[3];
    const float* Wl0      = (const float*)d_in[4];
    const float* bl0      = (const float*)d_in[5];
    const float* Wr0      = (const float*)d_in[6];
    const float* Wl1      = (const float*)d_in[7];
    const float* bl1      = (const float*)d_in[8];
    const float* Wr1      = (const float*)d_in[9];
    const float* Wout     = (const float*)d_in[10];
    const float* bout     = (const float*)d_in[11];
    float* out = (float*)d_out;

    const int* esrc = edge_idx;
    const int* edst = edge_idx + N_EDGES;

    // workspace layout: NXCD replicated copies of Pb0 and Pb1 (each copy
    // (N+1)*64 bf16 = 6.4MB; 8 copies = 51.2MB per array), then H, ebuf,
    // cnt, psum. Total ~120MB < workspace.
    __hip_bfloat16* Pb0 = (__hip_bfloat16*)d_ws;               // NXCD copies
    __hip_bfloat16* Pb1 = Pb0 + (size_t)NXCD * CPY;            // NXCD copies
    float* H = (float*)(Pb1 + (size_t)NXCD * CPY);             // N*64 f32
    int* ebuf = (int*)(H + (size_t)N_NODES * 64);              // NB*CAP ints
    int* cnt = ebuf + (size_t)NB_BKT * BKT_CAP;                // NB*CNT_STRIDE ints
    float* psum = (float*)(cnt + (size_t)NB_BKT * CNT_STRIDE); // G*64 floats

    const int BLK = 256;

    // one memset zeroes padded bucket counters + pool accumulators (contiguous)
    hipMemsetAsync(cnt, 0, (NB_BKT * CNT_STRIDE + N_GRAPHS * 64) * sizeof(int), stream);

    // combo: bucket multi-split (196 blocks) + layer-0 xform (782 blocks)
    k_combo<<<EB_BLOCKS + XFORM_BLOCKS, BLK, 0, stream>>>(
        esrc, edst, cnt, ebuf, node_ids, emb, Wl0, bl0, Wr0, Pb0, Pb1, H);

    // fused layer-0 aggregate (XCD-local copy, src-phased) + layer-1 transform
    k_fused1<<<XFORM_BLOCKS, BLK, 0, stream>>>(cnt, ebuf, Pb0, Wl1, bl1, Wr1,
                                               Pb1, H);

    // layer-1 aggregate (XCD-local copy, src-phased) fused with graph pooling
    k_agg2_pool<<<NB_BKT, BLK, 0, stream>>>(cnt, ebuf, Pb1, H, batch, psum);

    // output projection
    k_out<<<(N_GRAPHS + 3) / 4, BLK, 0, stream>>>(batch, psum, Wout, bout, out);
}

// Round 10
// 186.009 us; speedup vs baseline: 1.1024x; 1.1024x over previous
//
#include <hip/hip_runtime.h>
#include <hip/hip_bf16.h>

#define N_NODES 50000
#define N_EDGES 800000
#define EMB 64
#define HID 64
#define N_CLASSES 10
#define N_GRAPHS 512

#define BKT_SHIFT 6
#define BKT_NODES 64
#define NB_BKT ((N_NODES + BKT_NODES - 1) / BKT_NODES)   // 782
#define BKT_CAP 1408     // mean 1024 + 12 sigma
#define CNT_STRIDE 16    // one counter per 64B line: kills cross-XCD false sharing
#define EB_CHUNK 4096
#define EB_PER_THR (EB_CHUNK / 256)                      // 16
#define EB_BLOCKS ((N_EDGES + EB_CHUNK - 1) / EB_CHUNK)  // 196
#define XFORM_BLOCKS ((N_NODES + 63) / 64)               // 782
#define XPAD 68
#define ZROW N_NODES                                      // sentinel zero-row
#define LCSR_SZ 1856      // sum of 8-aligned padded degrees: 1408 + 64*7
#define LCSR_FULL 1864    // +8 guard so clamped loads of empty regions stay in-array

// bf16 row accumulate: 8 bf16 dims (uint4) into fp32[8]
#define ACC8(vv, A)                                                            \
    do {                                                                       \
        A[0] += __uint_as_float((vv).x << 16);                                 \
        A[1] += __uint_as_float((vv).x & 0xFFFF0000u);                         \
        A[2] += __uint_as_float((vv).y << 16);                                 \
        A[3] += __uint_as_float((vv).y & 0xFFFF0000u);                         \
        A[4] += __uint_as_float((vv).z << 16);                                 \
        A[5] += __uint_as_float((vv).z & 0xFFFF0000u);                         \
        A[6] += __uint_as_float((vv).w << 16);                                 \
        A[7] += __uint_as_float((vv).w & 0xFFFF0000u);                         \
    } while (0)

// Build this bucket's CSR in LDS. Regions 8-aligned, pads = ZROW sentinel
// (points at a zeroed Pb row) -> branch-free chunked aggregation.
__device__ __forceinline__ void build_local_csr(
    int bucket, const int* __restrict__ cnt, const int* __restrict__ ebuf,
    unsigned short* lcsr, int* nhist, int* sval, int* sexcl, int* ncur) {
    int tid = threadIdx.x;
    int bs = bucket * BKT_CAP;
    int ne = min(cnt[bucket * CNT_STRIDE], BKT_CAP);   // defensive clamp
    if (tid < BKT_NODES) { nhist[tid] = 0; ncur[tid] = 0; }
    for (int i = tid; i < LCSR_FULL; i += 256) lcsr[i] = (unsigned short)ZROW;
    __syncthreads();
    int held[6];                 // 6*256 = 1536 >= BKT_CAP
    int nh = 0;
    for (int i = tid; i < ne; i += 256) held[nh++] = ebuf[bs + i];
#pragma unroll
    for (int j = 0; j < 6; j++)
        if (j < nh) atomicAdd(&nhist[held[j] >> 16], 1);
    __syncthreads();
    if (tid < 64) {            // wave 0: scan of PADDED degrees for offsets
        int v = nhist[tid];
        int p = (v + 7) & ~7;
        int s = p;
#pragma unroll
        for (int off = 1; off < 64; off <<= 1) {
            int u = __shfl_up(s, off, 64);
            if (tid >= off) s += u;
        }
        sval[tid] = v;
        sexcl[tid] = s - p;
    }
    __syncthreads();
#pragma unroll
    for (int j = 0; j < 6; j++)
        if (j < nh) {
            int p = held[j];
            int l = p >> 16;
            int r = atomicAdd(&ncur[l], 1);
            lcsr[sexcl[l] + r] = (unsigned short)(p & 0xFFFF);
        }
    __syncthreads();
}

// Dual-node mean aggregation, 4-wide chunks, 2-deep software pipeline:
// chunk c+1's 8 loads are in flight while chunk c accumulates.
// Sentinel-padded CSR -> no tails; clamped loads + predicated ACC.
__device__ __forceinline__ void agg2(
    int sA, int dA, int sB, int dB, int sl,
    const unsigned short* lcsr, const __hip_bfloat16* __restrict__ Pb,
    float oA[8], float oB[8]) {
    float a0[8], a1[8], b0[8], b1[8];
#pragma unroll
    for (int j = 0; j < 8; j++) { a0[j] = 0.f; a1[j] = 0.f; b0[j] = 0.f; b1[j] = 0.f; }
    int nA = (dA + 3) >> 2, nB = (dB + 3) >> 2;
    int n = max(nA, nB);
    int mA = max(nA - 1, 0), mB = max(nB - 1, 0);
    if (n > 0) {
        uint4 A0[4], A1[4], B0[4], B1[4];
#define LD4(D, base_)                                                          \
        {                                                                      \
            int _p = (base_);                                                  \
            D[0] = ((const uint4*)(Pb + (size_t)lcsr[_p + 0] * 64))[sl];       \
            D[1] = ((const uint4*)(Pb + (size_t)lcsr[_p + 1] * 64))[sl];       \
            D[2] = ((const uint4*)(Pb + (size_t)lcsr[_p + 2] * 64))[sl];       \
            D[3] = ((const uint4*)(Pb + (size_t)lcsr[_p + 3] * 64))[sl];       \
        }
#define AC4(S, X0, X1)                                                         \
        { ACC8(S[0], X0); ACC8(S[1], X1); ACC8(S[2], X0); ACC8(S[3], X1); }
        LD4(A0, sA); LD4(B0, sB);
        int c = 1;
        for (; c + 1 < n; c += 2) {
            LD4(A1, sA + 4 * min(c, mA)); LD4(B1, sB + 4 * min(c, mB));
            if (c - 1 < nA) AC4(A0, a0, a1);
            if (c - 1 < nB) AC4(B0, b0, b1);
            LD4(A0, sA + 4 * min(c + 1, mA)); LD4(B0, sB + 4 * min(c + 1, mB));
            if (c < nA) AC4(A1, a0, a1);
            if (c < nB) AC4(B1, b0, b1);
        }
        if (c < n) {
            LD4(A1, sA + 4 * min(c, mA)); LD4(B1, sB + 4 * min(c, mB));
            if (c - 1 < nA) AC4(A0, a0, a1);
            if (c - 1 < nB) AC4(B0, b0, b1);
            if (c < nA) AC4(A1, a0, a1);
            if (c < nB) AC4(B1, b0, b1);
        } else {
            if (c - 1 < nA) AC4(A0, a0, a1);
            if (c - 1 < nB) AC4(B0, b0, b1);
        }
#undef LD4
#undef AC4
    }
    float invA = (dA > 0) ? 1.0f / (float)dA : 0.0f;
    float invB = (dB > 0) ? 1.0f / (float)dB : 0.0f;
#pragma unroll
    for (int j = 0; j < 8; j++) {
        oA[j] = (a0[j] + a1[j]) * invA;
        oB[j] = (b0[j] + b1[j]) * invB;
    }
}

// m += Q (from H), relu, stage 8 dims into dst[sl*8..sl*8+7]
__device__ __forceinline__ void finish_row(int node, int sl,
                                           const float* __restrict__ H,
                                           float m[8], float* dst) {
    if (node < N_NODES) {
        size_t off = (size_t)node * 64 + sl * 8;
        float4 q0 = *(const float4*)&H[off];
        float4 q1 = *(const float4*)&H[off + 4];
        m[0] = fmaxf(m[0] + q0.x, 0.f);
        m[1] = fmaxf(m[1] + q0.y, 0.f);
        m[2] = fmaxf(m[2] + q0.z, 0.f);
        m[3] = fmaxf(m[3] + q0.w, 0.f);
        m[4] = fmaxf(m[4] + q1.x, 0.f);
        m[5] = fmaxf(m[5] + q1.y, 0.f);
        m[6] = fmaxf(m[6] + q1.z, 0.f);
        m[7] = fmaxf(m[7] + q1.w, 0.f);
    } else {
#pragma unroll
        for (int j = 0; j < 8; j++) m[j] = 0.f;
    }
    *(float4*)&dst[sl * 8] = make_float4(m[0], m[1], m[2], m[3]);
    *(float4*)&dst[sl * 8 + 4] = make_float4(m[4], m[5], m[6], m[7]);
}

// Fused dual-weight 64x64x64 GEMM from staged sX. Weights read from global
// (L1-resident 16KB each, 256B/wave/instruction). One barrier-free pass:
// Pb = bf16(sX @ Wl)  and  Qout = sX @ Wr + bl.
__device__ __forceinline__ void gemm_dual_from_sX(
    int tile, int t, const float* sX,
    const float* __restrict__ Wl, const float* __restrict__ Wr,
    const float* __restrict__ bl,
    __hip_bfloat16* __restrict__ Pb, float* __restrict__ Qout) {
    int dg = t & 15, ng = t >> 4;
    float accL[4][4], accR[4][4];
#pragma unroll
    for (int i = 0; i < 4; i++)
#pragma unroll
        for (int j = 0; j < 4; j++) { accL[i][j] = 0.f; accR[i][j] = 0.f; }
#pragma unroll 4
    for (int k = 0; k < 64; k++) {
        float4 wl = ((const float4*)Wl)[k * 16 + dg];
        float4 wr = ((const float4*)Wr)[k * 16 + dg];
#pragma unroll
        for (int i = 0; i < 4; i++) {
            float xv = sX[(ng + i * 16) * XPAD + k];
            accL[i][0] = fmaf(xv, wl.x, accL[i][0]);
            accL[i][1] = fmaf(xv, wl.y, accL[i][1]);
            accL[i][2] = fmaf(xv, wl.z, accL[i][2]);
            accL[i][3] = fmaf(xv, wl.w, accL[i][3]);
            accR[i][0] = fmaf(xv, wr.x, accR[i][0]);
            accR[i][1] = fmaf(xv, wr.y, accR[i][1]);
            accR[i][2] = fmaf(xv, wr.z, accR[i][2]);
            accR[i][3] = fmaf(xv, wr.w, accR[i][3]);
        }
    }
    float4 blv = ((const float4*)bl)[dg];
#pragma unroll
    for (int i = 0; i < 4; i++) {
        int node = tile + ng + i * 16;
        if (node < N_NODES) {
            union { ushort4 u; __hip_bfloat16 h[4]; } pk;
            pk.h[0] = __float2bfloat16(accL[i][0]);
            pk.h[1] = __float2bfloat16(accL[i][1]);
            pk.h[2] = __float2bfloat16(accL[i][2]);
            pk.h[3] = __float2bfloat16(accL[i][3]);
            *(ushort4*)&Pb[(size_t)node * 64 + dg * 4] = pk.u;
            *(float4*)&Qout[(size_t)node * 64 + dg * 4] =
                make_float4(accR[i][0] + blv.x, accR[i][1] + blv.y,
                            accR[i][2] + blv.z, accR[i][3] + blv.w);
        }
    }
}

// ---------------- combo: bucket multi-split (blocks 0..EB) + layer-0 xform ----------------
__global__ __launch_bounds__(256) void k_combo(
    const int* __restrict__ esrc, const int* __restrict__ edst,
    int* __restrict__ cnt, int* __restrict__ ebuf,
    const int* __restrict__ ids, const float* __restrict__ emb,
    const float* __restrict__ Wl, const float* __restrict__ bl,
    const float* __restrict__ Wr,
    __hip_bfloat16* __restrict__ Pb, __hip_bfloat16* __restrict__ Pb1z,
    float* __restrict__ Qout) {
    __shared__ float sX[64 * XPAD];     // bsplit path aliases as int scratch
    int t = threadIdx.x;
    if (blockIdx.x < EB_BLOCKS) {
        // block 0 additionally zeroes the Pb0/Pb1 sentinel rows (ZROW)
        if (blockIdx.x == 0 && t < 16) {
            uint4 z = make_uint4(0u, 0u, 0u, 0u);
            if (t < 8) ((uint4*)(Pb + (size_t)ZROW * 64))[t] = z;
            else       ((uint4*)(Pb1z + (size_t)ZROW * 64))[t - 8] = z;
        }
        // ---- bsplit path (single pass over edst; dests in registers) ----
        int* h = (int*)sX;                 // NB_BKT
        int* bbase = h + NB_BKT;           // NB_BKT
        int* cur = bbase + NB_BKT;         // NB_BKT  (3*782*4 = 9.4KB < 17.4KB)
        for (int i = t; i < NB_BKT; i += 256) { h[i] = 0; cur[i] = 0; }
        __syncthreads();
        int base = blockIdx.x * EB_CHUNK;
        int end = min(base + EB_CHUNK, N_EDGES);
        int dreg[EB_PER_THR];
        int nd = 0;
        for (int i = base + t; i < end; i += 256) dreg[nd++] = edst[i];
#pragma unroll
        for (int j = 0; j < EB_PER_THR; j++)
            if (j < nd) atomicAdd(&h[dreg[j] >> BKT_SHIFT], 1);
        __syncthreads();
        for (int i = t; i < NB_BKT; i += 256)
            if (h[i]) bbase[i] = i * BKT_CAP + atomicAdd(&cnt[i * CNT_STRIDE], h[i]);
        __syncthreads();
        {
            int j = 0;
            for (int i = base + t; i < end; i += 256, j++) {
                int d = dreg[j], s = esrc[i];
                int b = d >> BKT_SHIFT;
                int r = atomicAdd(&cur[b], 1);
                int slot = bbase[b] + r;
                if (slot < (b + 1) * BKT_CAP)          // defensive clamp
                    ebuf[slot] = ((d & (BKT_NODES - 1)) << 16) | s;
            }
        }
        return;
    }
    // ---- xform0 path: stage emb rows, fused dual GEMM ----
    int tile = (blockIdx.x - EB_BLOCKS) * 64;
    for (int i = t; i < 64 * 16; i += 256) {
        int r = i >> 4, c = i & 15;
        int node = tile + r;
        float4 v = make_float4(0.f, 0.f, 0.f, 0.f);
        if (node < N_NODES)
            v = ((const float4*)(emb + (size_t)ids[node] * 64))[c];
        *(float4*)&sX[r * XPAD + c * 4] = v;
    }
    __syncthreads();
    gemm_dual_from_sX(tile, t, sX, Wl, Wr, bl, Pb, Qout);
}

// ---------------- fused: LDS CSR + layer-0 aggregate + layer-1 xform ----------------
__global__ __launch_bounds__(256, 4) void k_fused1(
    const int* __restrict__ cnt, const int* __restrict__ ebuf,
    const __hip_bfloat16* __restrict__ Pb0, const float* __restrict__ Wl,
    const float* __restrict__ bl, const float* __restrict__ Wr,
    __hip_bfloat16* __restrict__ Pb1, float* __restrict__ H) {
    __shared__ float sX[64 * XPAD];
    __shared__ unsigned short lcsr[LCSR_FULL];
    __shared__ int nhist[BKT_NODES], sval[BKT_NODES], sexcl[BKT_NODES], ncur[BKT_NODES];
    int t = threadIdx.x;
    int tile = blockIdx.x * 64;
    build_local_csr(blockIdx.x, cnt, ebuf, lcsr, nhist, sval, sexcl, ncur);
    // phase (a): pipelined dual-node aggregate, H0 = relu(mean+Q0) -> sX
    int grp = t >> 3, sl = t & 7;
    int ln0 = grp * 2, ln1 = ln0 + 1;
    float mA[8], mB[8];
    agg2(sexcl[ln0], sval[ln0], sexcl[ln1], sval[ln1], sl, lcsr, Pb0, mA, mB);
    finish_row(tile + ln0, sl, H, mA, &sX[ln0 * XPAD]);
    finish_row(tile + ln1, sl, H, mB, &sX[ln1 * XPAD]);
    __syncthreads();
    // phase (b): fused dual GEMM -> Pb1 (bf16) and H (Q1)
    gemm_dual_from_sX(tile, t, sX, Wl, Wr, bl, Pb1, H);
}

// ---------------- layer-1 aggregate + pooling (block = bucket = 64 nodes) ----------------
__global__ __launch_bounds__(256, 4) void k_agg2_pool(
    const int* __restrict__ cnt, const int* __restrict__ ebuf,
    const __hip_bfloat16* __restrict__ Pb, const float* __restrict__ H,
    const int* __restrict__ batch, float* __restrict__ psum) {
    __shared__ float sPool[64 * 64];
    __shared__ unsigned short lcsr[LCSR_FULL];
    __shared__ int nhist[BKT_NODES], sval[BKT_NODES], sexcl[BKT_NODES], ncur[BKT_NODES];
    __shared__ int sLg[64];
    int t = threadIdx.x;
    int nb = blockIdx.x * 64;
    int gmin = batch[nb];
    if (t < 64) {
        int node = nb + t;
        sLg[t] = batch[node < N_NODES ? node : (N_NODES - 1)] - gmin;
    }
    build_local_csr(blockIdx.x, cnt, ebuf, lcsr, nhist, sval, sexcl, ncur);
    int grp = t >> 3, sl = t & 7;
    int ln0 = grp * 2, ln1 = ln0 + 1;
    float mA[8], mB[8];
    agg2(sexcl[ln0], sval[ln0], sexcl[ln1], sval[ln1], sl, lcsr, Pb, mA, mB);
    finish_row(nb + ln0, sl, H, mA, &sPool[ln0 * 64]);
    finish_row(nb + ln1, sl, H, mB, &sPool[ln1 * 64]);
    __syncthreads();
    // segmented per-dim sum over this bucket's 64 rows (batch sorted).
    int d = t & 63, q = t >> 6;
    int n0 = q * 16;
    float run = 0.f;
    int cur = sLg[n0];
    for (int n = n0; n < n0 + 16; n++) {
        int lg = sLg[n];
        if (lg != cur) {
            if (run != 0.f)
                atomicAdd(&psum[(size_t)(gmin + cur) * 64 + d], run);
            run = 0.f;
            cur = lg;
        }
        run += sPool[n * 64 + d];
    }
    if (run != 0.f)
        atomicAdd(&psum[(size_t)(gmin + cur) * 64 + d], run);
}

// ---------------- output projection ----------------
__device__ __forceinline__ int lower_bound_batch(const int* __restrict__ batch, int val) {
    int lo = 0, hi = N_NODES;
    while (lo < hi) {
        int mid = (lo + hi) >> 1;
        if (batch[mid] < val) lo = mid + 1; else hi = mid;
    }
    return lo;
}

__global__ __launch_bounds__(256) void k_out(
    const int* __restrict__ batch, const float* __restrict__ psum,
    const float* __restrict__ Wout, const float* __restrict__ bout,
    float* __restrict__ out) {
    int w = threadIdx.x >> 6, lane = threadIdx.x & 63;
    int g = blockIdx.x * 4 + w;
    if (g >= N_GRAPHS) return;
    int s0 = lower_bound_batch(batch, g);
    int s1 = lower_bound_batch(batch, g + 1);
    int cntg = s1 - s0;
    float inv = (cntg > 0) ? 1.0f / (float)cntg : 0.0f;
    float pooled = psum[(size_t)g * 64 + lane] * inv;
#pragma unroll
    for (int c = 0; c < N_CLASSES; c++) {
        float v = pooled * Wout[lane * N_CLASSES + c];
#pragma unroll
        for (int off = 32; off > 0; off >>= 1) v += __shfl_down(v, off, 64);
        if (lane == 0) out[(size_t)g * N_CLASSES + c] = v + bout[c];
    }
}

// ---------------- launch ----------------

extern "C" void kernel_launch(void* const* d_in, const int* in_sizes, int n_in,
                              void* d_out, int out_size, void* d_ws, size_t ws_size,
                              hipStream_t stream) {
    const int*   node_ids = (const int*)d_in[0];
    const int*   edge_idx = (const int*)d_in[1];   // [2, E] row-major
    const int*   batch    = (const int*)d_in[2];
    const float* emb      = (const float*)d_in[3];
    const float* Wl0      = (const float*)d_in[4];
    const float* bl0      = (const float*)d_in[5];
    const float* Wr0      = (const float*)d_in[6];
    const float* Wl1      = (const float*)d_in[7];
    const float* bl1      = (const float*)d_in[8];
    const float* Wr1      = (const float*)d_in[9];
    const float* Wout     = (const float*)d_in[10];
    const float* bout     = (const float*)d_in[11];
    float* out = (float*)d_out;

    const int* esrc = edge_idx;
    const int* edst = edge_idx + N_EDGES;

    // workspace layout (Pb arrays have N+1 rows: last row = ZROW sentinel zeros)
    __hip_bfloat16* Pb0 = (__hip_bfloat16*)d_ws;               // (N+1)*64 bf16
    __hip_bfloat16* Pb1 = Pb0 + (size_t)(N_NODES + 1) * 64;    // (N+1)*64 bf16
    float* H = (float*)(Pb1 + (size_t)(N_NODES + 1) * 64);     // N*64 f32
    int* ebuf = (int*)(H + (size_t)N_NODES * 64);              // NB*CAP ints
    int* cnt = ebuf + (size_t)NB_BKT * BKT_CAP;                // NB*CNT_STRIDE ints
    float* psum = (float*)(cnt + (size_t)NB_BKT * CNT_STRIDE); // G*64 floats

    const int BLK = 256;

    // one memset zeroes padded bucket counters + pool accumulators (contiguous)
    hipMemsetAsync(cnt, 0, (NB_BKT * CNT_STRIDE + N_GRAPHS * 64) * sizeof(int), stream);

    // combo: bucket multi-split (196 blocks) + layer-0 xform (782 blocks)
    k_combo<<<EB_BLOCKS + XFORM_BLOCKS, BLK, 0, stream>>>(
        esrc, edst, cnt, ebuf, node_ids, emb, Wl0, bl0, Wr0, Pb0, Pb1, H);

    // fused layer-0 aggregate (LDS CSR) + layer-1 transform
    k_fused1<<<XFORM_BLOCKS, BLK, 0, stream>>>(cnt, ebuf, Pb0, Wl1, bl1, Wr1,
                                               Pb1, H);

    // layer-1 aggregate (LDS CSR) fused with graph pooling
    k_agg2_pool<<<NB_BKT, BLK, 0, stream>>>(cnt, ebuf, Pb1, H, batch, psum);

    // output projection
    k_out<<<(N_GRAPHS + 3) / 4, BLK, 0, stream>>>(batch, psum, Wout, bout, out);
}